// Round 2
// baseline (607.287 us; speedup 1.0000x reference)
//
#include <hip/hip_runtime.h>
#include <hip/hip_bf16.h>
#include <math.h>

#define B_SZ 8
#define D_MODEL 2048
#define H_N 16
#define D_H 128
#define D_V 128
#define R_DIM 64
#define W_CTX 8192
#define NB 64
#define QKV_DIM 384
#define N_FEAT 6144
#define SPLIT 2

// ---------------- workspace layout (float offsets) ----------------
#define WS_H      0          // 8*2048      = 16384
#define WS_QKV    16384      // 8*6144      = 49152
#define WS_QL     65536      // 128*64      = 8192
#define WS_KL     73728
#define WS_VL     81920
#define WS_ATTN   90112
#define WS_SCORES 98304      // [b][n][h]   = 8192
#define WS_PART   106496     // 128*SPLIT*66 = 16896
#define WS_INT    123392     // int region starts here
#define WI_TOPK   0          // 8*2
#define WI_CNT    16         // 8
#define WI_RIDX   24         // 8*8192

__device__ __forceinline__ float softplus_f(float x) {
    return fmaxf(x, 0.f) + log1pf(expf(-fabsf(x)));
}
__device__ __forceinline__ float gelu_f(float x) {
    return 0.5f * x * (1.f + erff(x * 0.70710678118654752f));
}
__device__ __forceinline__ float sigmoid_f(float x) {
    return 1.f / (1.f + expf(-x));
}

__device__ __forceinline__ float block_reduce_sum_256(float v, float* red) {
    int tid = threadIdx.x;
    red[tid] = v; __syncthreads();
    #pragma unroll
    for (int o = 128; o > 0; o >>= 1) { if (tid < o) red[tid] += red[tid + o]; __syncthreads(); }
    float r = red[0]; __syncthreads();
    return r;
}
__device__ __forceinline__ float block_reduce_max_256(float v, float* red) {
    int tid = threadIdx.x;
    red[tid] = v; __syncthreads();
    #pragma unroll
    for (int o = 128; o > 0; o >>= 1) { if (tid < o) red[tid] = fmaxf(red[tid], red[tid + o]); __syncthreads(); }
    float r = red[0]; __syncthreads();
    return r;
}

// ------------------- 1. LayerNorm (8 rows) -------------------
__global__ __launch_bounds__(256) void ln_kernel(const float* __restrict__ x,
                                                 const float* __restrict__ g,
                                                 const float* __restrict__ be,
                                                 float* __restrict__ h) {
    int b = blockIdx.x, tid = threadIdx.x;
    __shared__ float red[256];
    const float* xr = x + b * D_MODEL;
    float vals[8];
    float s = 0.f;
    #pragma unroll
    for (int i = 0; i < 8; ++i) { float v = xr[i * 256 + tid]; vals[i] = v; s += v; }
    float mu = block_reduce_sum_256(s, red) * (1.f / D_MODEL);
    float s2 = 0.f;
    #pragma unroll
    for (int i = 0; i < 8; ++i) { float d = vals[i] - mu; s2 += d * d; }
    float var = block_reduce_sum_256(s2, red) * (1.f / D_MODEL);
    float inv = 1.f / sqrtf(var + 1e-5f);
    #pragma unroll
    for (int i = 0; i < 8; ++i) {
        int idx = i * 256 + tid;
        h[b * D_MODEL + idx] = (vals[i] - mu) * inv * g[idx] + be[idx];
    }
}

// ------------------- 2. qkv = h @ W_qkv^T  (8 x 2048 x 6144) -------------------
// wave handles 4 output columns for all 8 batch rows; W reads fully coalesced float4.
__global__ __launch_bounds__(256) void qkv_kernel(const float* __restrict__ hbuf,
                                                  const float* __restrict__ Wq,
                                                  float* __restrict__ qkv) {
    int wave = threadIdx.x >> 6, lane = threadIdx.x & 63;
    int j0 = (blockIdx.x * 4 + wave) * 4;
    float acc[4][8];
    #pragma unroll
    for (int c = 0; c < 4; ++c)
        #pragma unroll
        for (int b = 0; b < 8; ++b) acc[c][b] = 0.f;

    #pragma unroll
    for (int i = 0; i < 8; ++i) {
        int k = i * 256 + lane * 4;
        float4 hv[8];
        #pragma unroll
        for (int b = 0; b < 8; ++b)
            hv[b] = *reinterpret_cast<const float4*>(hbuf + b * D_MODEL + k);
        #pragma unroll
        for (int c = 0; c < 4; ++c) {
            float4 wv = *reinterpret_cast<const float4*>(Wq + (size_t)(j0 + c) * D_MODEL + k);
            #pragma unroll
            for (int b = 0; b < 8; ++b)
                acc[c][b] += wv.x * hv[b].x + wv.y * hv[b].y + wv.z * hv[b].z + wv.w * hv[b].w;
        }
    }
    #pragma unroll
    for (int c = 0; c < 4; ++c) {
        #pragma unroll
        for (int b = 0; b < 8; ++b) {
            float v = acc[c][b];
            #pragma unroll
            for (int o = 32; o > 0; o >>= 1) v += __shfl_down(v, o);
            if (lane == 0) qkv[b * N_FEAT + j0 + c] = v;
        }
    }
}

// ------------------- 3. Q_L/K_L/V_L + block scores, per (b,h) -------------------
__global__ __launch_bounds__(64) void proj_kernel(const float* __restrict__ qkv,
                                                  const float* __restrict__ Eq,
                                                  const float* __restrict__ Ek,
                                                  const float* __restrict__ Ev,
                                                  const float* __restrict__ bmeans,
                                                  float* __restrict__ QL, float* __restrict__ KL,
                                                  float* __restrict__ VL, float* __restrict__ scores) {
    int bh = blockIdx.x; int b = bh >> 4, hh = bh & 15; int r = threadIdx.x;
    __shared__ float sh[QKV_DIM];
    __shared__ float qls[R_DIM];
    const float* row = qkv + b * N_FEAT + hh * QKV_DIM;
    for (int i = r; i < QKV_DIM; i += 64) sh[i] = row[i];
    __syncthreads();
    const float* eq = Eq + (size_t)hh * D_H * R_DIM;
    const float* ek = Ek + (size_t)hh * D_H * R_DIM;
    const float* ev = Ev + (size_t)hh * D_V * R_DIM;
    float ql = 0.f, kl = 0.f, vl = 0.f;
    #pragma unroll 4
    for (int d = 0; d < 128; ++d) {
        ql += sh[d]       * eq[d * R_DIM + r];
        kl += sh[128 + d] * ek[d * R_DIM + r];
        vl += sh[256 + d] * ev[d * R_DIM + r];
    }
    QL[bh * R_DIM + r] = ql;
    KL[bh * R_DIM + r] = kl;
    VL[bh * R_DIM + r] = vl;
    qls[r] = ql;
    __syncthreads();
    // scores[b,h,n] = (Q_L . block_means[n,b,h,:]) / 8 * gamma^(NB-1-n)
    int n = r;
    const float* bm = bmeans + ((size_t)n * B_SZ * H_N + bh) * R_DIM;
    float s = 0.f;
    #pragma unroll 8
    for (int rr = 0; rr < R_DIM; ++rr) s += qls[rr] * bm[rr];
    s *= 0.125f;
    s *= powf(0.97f, (float)(NB - 1 - n));
    scores[(b * NB + n) * H_N + hh] = s;   // layout [b][n][h]
}

// ------------------- 4. per-batch top-2 + ordered routed compaction -------------------
__global__ __launch_bounds__(256) void route_kernel(const float* __restrict__ scores,
                                                    const int* __restrict__ block_ids,
                                                    const int* __restrict__ cur_id,
                                                    int* __restrict__ topk,
                                                    int* __restrict__ ridx,
                                                    int* __restrict__ rcnt) {
    int b = blockIdx.x, tid = threadIdx.x;
    __shared__ float sm[NB];
    __shared__ int t0s, t1s;
    __shared__ int cs[256];
    __shared__ int off[257];
    if (tid < NB) {
        float s = 0.f;
        const float* p = scores + (b * NB + tid) * H_N;
        #pragma unroll
        for (int j = 0; j < H_N; ++j) s += p[j];
        sm[tid] = s * (1.f / H_N);
    }
    __syncthreads();
    if (tid == 0) {
        int i0 = 0; float v0 = sm[0];
        for (int n = 1; n < NB; ++n) if (sm[n] > v0) { v0 = sm[n]; i0 = n; }
        int i1 = -1; float v1 = -3.4e38f;
        for (int n = 0; n < NB; ++n) { if (n == i0) continue; if (sm[n] > v1) { v1 = sm[n]; i1 = n; } }
        t0s = i0; t1s = i1;
        topk[b * 2] = i0; topk[b * 2 + 1] = i1;
    }
    __syncthreads();
    int t0 = t0s, t1 = t1s, cur = cur_id[0];
    const int CH = W_CTX / 256;  // 32, contiguous chunk per thread -> ordered output
    int base = tid * CH;
    const int* bi = block_ids + (size_t)b * W_CTX;
    int cnt = 0;
    for (int i = 0; i < CH; ++i) {
        int id = bi[base + i];
        if (id == t0 || id == t1 || id == cur) ++cnt;
    }
    cs[tid] = cnt; __syncthreads();
    if (tid == 0) {
        int a = 0;
        for (int i = 0; i < 256; ++i) { off[i] = a; a += cs[i]; }
        off[256] = a; rcnt[b] = a;
    }
    __syncthreads();
    int o = off[tid];
    int* dst = ridx + (size_t)b * W_CTX;
    for (int i = 0; i < CH; ++i) {
        int id = bi[base + i];
        if (id == t0 || id == t1 || id == cur) dst[o++] = base + i;
    }
}

// ------------------- 5. sparse masked attention, split-K partials -------------------
__global__ __launch_bounds__(256) void attn_partial_kernel(const float* __restrict__ QL,
                                                           const float* __restrict__ Klat,
                                                           const float* __restrict__ Vlat,
                                                           const int* __restrict__ ridx,
                                                           const int* __restrict__ rcnt,
                                                           float* __restrict__ part) {
    int blk = blockIdx.x; int bh = blk / SPLIT; int sp = blk % SPLIT;
    int b = bh >> 4;
    int tid = threadIdx.x, wave = tid >> 6, lane = tid & 63;
    __shared__ float ql[R_DIM];
    __shared__ float pbuf[W_CTX / SPLIT];
    __shared__ float red[256];
    __shared__ float vred[4][R_DIM];
    if (tid < R_DIM) ql[tid] = QL[bh * R_DIM + tid];
    int cnt = rcnt[b];
    int m = (cnt > sp) ? (cnt - sp + SPLIT - 1) / SPLIT : 0;
    const int* ri = ridx + (size_t)b * W_CTX;
    __syncthreads();
    // logits: one wave per routed position, lane-coalesced K read, shuffle-reduce dot
    for (int j = wave; j < m; j += 4) {
        int w = ri[sp + j * SPLIT];
        float v = Klat[((size_t)bh * W_CTX + w) * R_DIM + lane] * ql[lane];
        #pragma unroll
        for (int o = 32; o > 0; o >>= 1) v += __shfl_down(v, o);
        if (lane == 0) pbuf[j] = v * 0.125f;
    }
    __syncthreads();
    float mx = -3.4e38f;
    for (int j = tid; j < m; j += 256) mx = fmaxf(mx, pbuf[j]);
    mx = block_reduce_max_256(mx, red);
    float ss = 0.f;
    for (int j = tid; j < m; j += 256) { float e = expf(pbuf[j] - mx); pbuf[j] = e; ss += e; }
    ss = block_reduce_sum_256(ss, red);
    // weighted V sum: one wave per position, lane-coalesced V read
    float acc = 0.f;
    for (int j = wave; j < m; j += 4) {
        int w = ri[sp + j * SPLIT];
        acc += pbuf[j] * Vlat[((size_t)bh * W_CTX + w) * R_DIM + lane];
    }
    vred[wave][lane] = acc; __syncthreads();
    float* pr = part + (size_t)(bh * SPLIT + sp) * 66;
    if (tid < R_DIM) pr[2 + tid] = vred[0][tid] + vred[1][tid] + vred[2][tid] + vred[3][tid];
    if (tid == 0) { pr[0] = mx; pr[1] = ss; }
}

__global__ __launch_bounds__(64) void attn_combine_kernel(const float* __restrict__ part,
                                                          float* __restrict__ attnb) {
    int bh = blockIdx.x; int r = threadIdx.x;
    float m = -3.4e38f;
    #pragma unroll
    for (int sp = 0; sp < SPLIT; ++sp) m = fmaxf(m, part[(size_t)(bh * SPLIT + sp) * 66]);
    float den = 0.f, num = 0.f;
    #pragma unroll
    for (int sp = 0; sp < SPLIT; ++sp) {
        const float* p = part + (size_t)(bh * SPLIT + sp) * 66;
        float w = expf(p[0] - m);
        den += p[1] * w;
        num += p[2 + r] * w;
    }
    attnb[bh * R_DIM + r] = num / den;
}

// ------------------- 6. fused epilogue per (b,h) -------------------
__global__ __launch_bounds__(256) void final_kernel(
    const float* __restrict__ QL, const float* __restrict__ KL, const float* __restrict__ VL,
    const float* __restrict__ attnb, const float* __restrict__ M, const float* __restrict__ z,
    const float* __restrict__ S_prev,
    const float* __restrict__ r1w, const float* __restrict__ r1b,
    const float* __restrict__ r2w, const float* __restrict__ r2b,
    const float* __restrict__ g1w, const float* __restrict__ g1b,
    const float* __restrict__ g2w, const float* __restrict__ g2b,
    const float* __restrict__ Ev,
    float* __restrict__ out, float* __restrict__ M_new,
    float* __restrict__ z_new, float* __restrict__ S_new) {
    int bh = blockIdx.x; int b = bh >> 4, hh = bh & 15; int tid = threadIdx.x;
    __shared__ __align__(16) float u[256];
    __shared__ __align__(16) float gh[256];
    __shared__ float qf[64], linv[64], olat[64], errv[64];
    __shared__ float rh[128];
    __shared__ float red[256];
    __shared__ float gouts[192];
    __shared__ float scal[3];

    if (tid < 64)       u[tid] = QL[bh * 64 + tid];
    else if (tid < 128) u[tid] = KL[bh * 64 + tid - 64];
    else if (tid < 192) u[tid] = VL[bh * 64 + tid - 128];
    else                u[tid] = attnb[bh * 64 + tid - 192];
    __syncthreads();

    // qf = softplus(Q_L); denom = qf.z + 1e-6
    float pz = 0.f;
    if (tid < 64) { float q = softplus_f(u[tid]); qf[tid] = q; pz = q * z[bh * 64 + tid]; }
    float denom = block_reduce_sum_256(pz, red) + 1e-6f;

    // lin
    if (tid < 64) {
        float a = 0.f; const float* Mp = M + (size_t)bh * 4096 + tid;
        #pragma unroll 8
        for (int r = 0; r < 64; ++r) a += qf[r] * Mp[r * 64];
        linv[tid] = a / denom;
    }
    // rh = gelu(Q_L @ r_fc1_w^T + b1)
    if (tid < 128) {
        float a = r1b[tid]; const float* wp = r1w + tid * 64;
        #pragma unroll 8
        for (int r = 0; r < 64; ++r) a += u[r] * wp[r];
        rh[tid] = gelu_f(a);
    }
    float pp = (tid < 128) ? rh[tid] * r2w[tid] : 0.f;
    float p_skip = sigmoid_f(block_reduce_sum_256(pp, red) + r2b[0]);

    // gh = gelu(u @ g_fc1_w^T + b)
    {
        float a = g1b[tid];
        const float4* wp = reinterpret_cast<const float4*>(g1w + (size_t)tid * 256);
        const float4* uu = reinterpret_cast<const float4*>(u);
        #pragma unroll 16
        for (int k = 0; k < 64; ++k) {
            float4 wv = wp[k], uv = uu[k];
            a += wv.x * uv.x + wv.y * uv.y + wv.z * uv.z + wv.w * uv.w;
        }
        gh[tid] = gelu_f(a);
    }
    __syncthreads();
    // gout = gh @ g_fc2_w^T + b
    if (tid < 192) {
        float a = g2b[tid];
        const float4* wp = reinterpret_cast<const float4*>(g2w + (size_t)tid * 256);
        const float4* gg = reinterpret_cast<const float4*>(gh);
        #pragma unroll 16
        for (int k = 0; k < 64; ++k) {
            float4 wv = wp[k], gv = gg[k];
            a += wv.x * gv.x + wv.y * gv.y + wv.z * gv.z + wv.w * gv.w;
        }
        gouts[tid] = a;
    }
    __syncthreads();
    if (tid == 0) { float s = 0.f; for (int i = 0;   i < 64;  ++i) s += gouts[i]; scal[0] = sigmoid_f(s * (1.f / 64)); }
    if (tid == 1) { float s = 0.f; for (int i = 64;  i < 128; ++i) s += gouts[i]; scal[1] = softplus_f(s * (1.f / 64)); }
    if (tid == 2) { float s = 0.f; for (int i = 128; i < 192; ++i) s += gouts[i]; scal[2] = softplus_f(s * (1.f / 64)); }
    // err = K_L @ M - V_L
    if (tid < 64) {
        float a = 0.f; const float* Mp = M + (size_t)bh * 4096 + tid;
        #pragma unroll 8
        for (int r = 0; r < 64; ++r) a += u[64 + r] * Mp[r * 64];
        errv[tid] = a - u[128 + tid];
    }
    __syncthreads();
    float alpha = scal[0], eta = scal[1], theta = scal[2];
    if (tid < 64) {
        olat[tid] = (1.f - p_skip) * u[192 + tid] + p_skip * linv[tid];
        z_new[bh * 64 + tid] = (1.f - alpha) * z[bh * 64 + tid] + softplus_f(u[64 + tid]);
    }
    // S_new / M_new (4096 elems)
    #pragma unroll
    for (int it = 0; it < 16; ++it) {
        int idx = it * 256 + tid;
        int r = idx >> 6, s = idx & 63;
        float g = u[64 + r] * errv[s];
        float sn = eta * S_prev[(size_t)bh * 4096 + idx] - theta * g;
        S_new[(size_t)bh * 4096 + idx] = sn;
        M_new[(size_t)bh * 4096 + idx] = (1.f - alpha) * M[(size_t)bh * 4096 + idx] + sn;
    }
    __syncthreads();
    // out = out_lat @ E_v^T  (per head, 128 dims)
    if (tid < 128) {
        float a = 0.f; const float* ep = Ev + ((size_t)hh * 128 + tid) * 64;
        #pragma unroll 8
        for (int r = 0; r < 64; ++r) a += olat[r] * ep[r];
        out[b * 2048 + hh * 128 + tid] = a;
    }
}

extern "C" void kernel_launch(void* const* d_in, const int* in_sizes, int n_in,
                              void* d_out, int out_size, void* d_ws, size_t ws_size,
                              hipStream_t stream) {
    const float* x      = (const float*)d_in[0];
    const float* ln_g   = (const float*)d_in[1];
    const float* ln_b   = (const float*)d_in[2];
    const float* W_qkv  = (const float*)d_in[3];
    const float* E_q    = (const float*)d_in[4];
    const float* E_k    = (const float*)d_in[5];
    const float* E_v    = (const float*)d_in[6];
    const float* K_lat  = (const float*)d_in[7];
    const float* V_lat  = (const float*)d_in[8];
    const float* bmeans = (const float*)d_in[9];
    const float* M      = (const float*)d_in[10];
    const float* z      = (const float*)d_in[11];
    const float* S_prev = (const float*)d_in[12];
    const float* r1w    = (const float*)d_in[13];
    const float* r1b    = (const float*)d_in[14];
    const float* r2w    = (const float*)d_in[15];
    const float* r2b    = (const float*)d_in[16];
    const float* g1w    = (const float*)d_in[17];
    const float* g1b    = (const float*)d_in[18];
    const float* g2w    = (const float*)d_in[19];
    const float* g2b    = (const float*)d_in[20];
    const int* block_ids = (const int*)d_in[21];
    const int* cur_id    = (const int*)d_in[22];

    float* ws    = (float*)d_ws;
    float* hbuf  = ws + WS_H;
    float* qkvb  = ws + WS_QKV;
    float* QLb   = ws + WS_QL;
    float* KLb   = ws + WS_KL;
    float* VLb   = ws + WS_VL;
    float* attnb = ws + WS_ATTN;
    float* scor  = ws + WS_SCORES;
    float* partb = ws + WS_PART;
    int*   iws   = (int*)(ws + WS_INT);
    int*   topk  = iws + WI_TOPK;
    int*   rcnt  = iws + WI_CNT;
    int*   ridx  = iws + WI_RIDX;

    float* out   = (float*)d_out;
    float* M_new = out + 16384;            // 8*2048
    float* z_new = out + 16384 + 524288;   // + 8*16*64*64
    float* S_new = out + 16384 + 524288 + 8192;

    ln_kernel<<<8, 256, 0, stream>>>(x, ln_g, ln_b, hbuf);
    qkv_kernel<<<N_FEAT / 16, 256, 0, stream>>>(hbuf, W_qkv, qkvb);
    proj_kernel<<<B_SZ * H_N, 64, 0, stream>>>(qkvb, E_q, E_k, E_v, bmeans, QLb, KLb, VLb, scor);
    route_kernel<<<B_SZ, 256, 0, stream>>>(scor, block_ids, cur_id, topk, ridx, rcnt);
    attn_partial_kernel<<<B_SZ * H_N * SPLIT, 256, 0, stream>>>(QLb, K_lat, V_lat, ridx, rcnt, partb);
    attn_combine_kernel<<<B_SZ * H_N, 64, 0, stream>>>(partb, attnb);
    final_kernel<<<B_SZ * H_N, 256, 0, stream>>>(QLb, KLb, VLb, attnb, M, z, S_prev,
        r1w, r1b, r2w, r2b, g1w, g1b, g2w, g2b, E_v,
        out, M_new, z_new, S_new);
}